// Round 14
// baseline (17759.944 us; speedup 1.0000x reference)
//
#include <hip/hip_runtime.h>
#include <math.h>

constexpr int NB    = 64;
constexpr int NT    = 256;
constexpr int NU    = 256;
constexpr int NMELc = 80;
constexpr int PREc  = 128;
constexpr int EMBc  = 15;
constexpr int NFc   = 128;
constexpr int ENCc  = 128;
constexpr int DECc  = 512;
constexpr int WMc   = 10;
constexpr int AKS   = 16;
constexpr size_t WSZ = (size_t)116 * 128 * 512;  // ushorts per weight plane (hi or lo)

using bf16x8 = __attribute__((ext_vector_type(8))) short;
using us8    = __attribute__((ext_vector_type(8))) unsigned short;
using f32x4  = __attribute__((ext_vector_type(4))) float;

__device__ __forceinline__ float sigm(float x) { return 1.0f / (1.0f + expf(-x)); }
__device__ __forceinline__ float softplusf(float x) { return fmaxf(x, 0.0f) + log1pf(expf(-fabsf(x))); }
__device__ __forceinline__ unsigned short f2bf(float f) {
  unsigned u = __builtin_bit_cast(unsigned, f);
  return (unsigned short)((u + 0x7FFFu + ((u >> 16) & 1u)) >> 16);
}
__device__ __forceinline__ float bf2f(unsigned short h) {
  return __builtin_bit_cast(float, (unsigned)h << 16);
}
// agent-relaxed bypass accessors (cross-XCD visible at L3, no cache maintenance)
__device__ __forceinline__ float ldF(const float* p) {
  return __hip_atomic_load(p, __ATOMIC_RELAXED, __HIP_MEMORY_SCOPE_AGENT);
}
__device__ __forceinline__ void stF(float* p, float v) {
  __hip_atomic_store(p, v, __ATOMIC_RELAXED, __HIP_MEMORY_SCOPE_AGENT);
}
__device__ __forceinline__ float2 ldF2(const float* p) {
  unsigned long long u = __hip_atomic_load((const unsigned long long*)p, __ATOMIC_RELAXED,
                                           __HIP_MEMORY_SCOPE_AGENT);
  return __builtin_bit_cast(float2, u);
}
__device__ __forceinline__ void stF2(float* p, float2 v) {
  __hip_atomic_store((unsigned long long*)p, __builtin_bit_cast(unsigned long long, v),
                     __ATOMIC_RELAXED, __HIP_MEMORY_SCOPE_AGENT);
}
__device__ __forceinline__ unsigned ldU(const unsigned* p) {
  return __hip_atomic_load(p, __ATOMIC_RELAXED, __HIP_MEMORY_SCOPE_AGENT);
}
__device__ __forceinline__ void stU(unsigned* p, unsigned v) {
  __hip_atomic_store(p, v, __ATOMIC_RELAXED, __HIP_MEMORY_SCOPE_AGENT);
}

// ---------------- generic dense ----------------
template <int K, int N, int RB>
__global__ void k_dense(const float* __restrict__ X, const float* __restrict__ W,
                        const float* __restrict__ bias, float* __restrict__ Y, int R) {
  __shared__ float xs[RB][K];
  int r0 = blockIdx.x * RB;
  int tid = threadIdx.x;  // 128
  for (int idx = tid; idx < RB * K; idx += 128) {
    int r = idx / K, k = idx % K;
    xs[r][k] = (r0 + r < R) ? X[(size_t)(r0 + r) * K + k] : 0.0f;
  }
  __syncthreads();
  int j = tid;
  if (j >= N) return;
  float acc[RB];
#pragma unroll
  for (int r = 0; r < RB; ++r) acc[r] = 0.f;
  for (int k = 0; k < K; ++k) {
    float w = W[(size_t)k * N + j];
#pragma unroll
    for (int r = 0; r < RB; ++r) acc[r] += xs[r][k] * w;
  }
  float bj = bias[j];
  for (int r = 0; r < RB; ++r)
    if (r0 + r < R) Y[(size_t)(r0 + r) * N + j] = acc[r] + bj;
}

// ---------------- embedding gather ----------------
__global__ void k_embed(const int* __restrict__ text, const float* __restrict__ emb,
                        float* __restrict__ out) {
  int idx = blockIdx.x * blockDim.x + threadIdx.x;
  if (idx >= NB * NU * EMBc) return;
  int c = idx % EMBc;
  int bu = idx / EMBc;
  int u = bu % NU, b = bu / NU;
  out[idx] = emb[text[u * NB + b] * EMBc + c];
}

// ---------------- merged conv weights ----------------
template <int CIN>
__global__ void k_weff(const float* __restrict__ w, const float* __restrict__ bb,
                       float* __restrict__ weff, float* __restrict__ beff) {
  int idx = blockIdx.x * blockDim.x + threadIdx.x;
  const int tot = 5 * CIN * NFc;
  if (idx < tot) {
    int f = idx % NFc;
    int tc = idx / NFc;
    int c = tc % CIN, t = tc / CIN;
    float m0 = (t == 2) ? 1.f : 0.f;
    float m1 = (t >= 1 && t <= 3) ? 1.f : 0.f;
    float w0 = w[((size_t)(0 * 5 + t) * CIN + c) * NFc + f];
    float w1 = w[((size_t)(1 * 5 + t) * CIN + c) * NFc + f];
    float w2 = w[((size_t)(2 * 5 + t) * CIN + c) * NFc + f];
    weff[idx] = w0 * m0 + w1 * m1 + w2;
  }
  if (idx < NFc) beff[idx] = bb[idx] + bb[NFc + idx] + bb[2 * NFc + idx];
}

// ---------------- conv stack ----------------
template <int CIN, bool RES>
__global__ void k_conv(const float* __restrict__ x, const float* __restrict__ weff,
                       const float* __restrict__ beff, float* __restrict__ y) {
  const int UT = 8;
  __shared__ float xs[(UT + 4) * CIN];
  int b = blockIdx.y, u0 = blockIdx.x * UT;
  int tid = threadIdx.x;  // 128
  for (int idx = tid; idx < (UT + 4) * CIN; idx += 128) {
    int c = idx % CIN;
    int uu = idx / CIN;
    int u = u0 + uu - 2;
    xs[idx] = (u >= 0 && u < NU) ? x[((size_t)b * NU + u) * CIN + c] : 0.f;
  }
  __syncthreads();
  int f = tid;
  float acc[UT];
#pragma unroll
  for (int r = 0; r < UT; ++r) acc[r] = beff[f];
  for (int t = 0; t < 5; ++t)
    for (int c = 0; c < CIN; ++c) {
      float w = weff[((size_t)t * CIN + c) * NFc + f];
#pragma unroll
      for (int r = 0; r < UT; ++r) acc[r] += xs[(r + t) * CIN + c] * w;
    }
  for (int r = 0; r < UT; ++r) {
    float v = fmaxf(acc[r], 0.f);
    if (RES) v += xs[(r + 2) * CIN + f];
    y[((size_t)b * NU + u0 + r) * NFc + f] = v;
  }
}

// ---------------- encoder x-part precompute: zx[d][u][b][512] (fp16) ----------------
__global__ __launch_bounds__(512) void k_zx(const float* __restrict__ Wf,
                                            const float* __restrict__ bf,
                                            const float* __restrict__ Wb,
                                            const float* __restrict__ bb_,
                                            const float* __restrict__ convt,
                                            _Float16* __restrict__ zx) {
  __shared__ float xs[8][128];
  int du = blockIdx.x;
  int d = du >> 8, u = du & 255;
  int bg = blockIdx.y;  // 8 batches
  const float* Wd = d ? Wb : Wf;
  const float* bd = d ? bb_ : bf;
  int upos_x = d ? (NU - 1 - u) : u;
  int tid = threadIdx.x;
  for (int idx = tid; idx < 8 * 128; idx += 512) {
    int bi = idx >> 7, k = idx & 127;
    xs[bi][k] = convt[((size_t)(bg * 8 + bi) * NU + upos_x) * 128 + k];
  }
  __syncthreads();
  int j = tid;
  float acc[8];
#pragma unroll
  for (int r = 0; r < 8; ++r) acc[r] = 0.f;
  for (int k = 0; k < 128; ++k) {
    float w = Wd[(size_t)k * 512 + j];
#pragma unroll
    for (int r = 0; r < 8; ++r) acc[r] += xs[r][k] * w;
  }
  float bj = bd[j];
#pragma unroll
  for (int r = 0; r < 8; ++r)
    zx[(((size_t)d * 256 + u) * 64 + bg * 8 + r) * 512 + j] = (_Float16)(acc[r] + bj);
}

// ---------------- persistent encoder: 32 blocks, block-local chains ----------------
__global__ __launch_bounds__(256) void k_encP2(const float* __restrict__ Wf,
                                               const float* __restrict__ Wb,
                                               const _Float16* __restrict__ zx,
                                               const float* __restrict__ text_mask,
                                               float* __restrict__ ctx) {
  __shared__ float hs[4][128];
  __shared__ float zs[4][512];
  int bid = blockIdx.x;
  int d = bid & 1, g = bid >> 1;
  int b0 = g * 4;
  const float* Wh = (d ? Wb : Wf) + (size_t)128 * 512;
  int tid = threadIdx.x;
  int q = tid >> 6, lane = tid & 63;
  int col0 = q * 128 + 2 * lane;
  float creg[2] = {0.f, 0.f};
  for (int idx = tid; idx < 512; idx += 256) hs[idx >> 7][idx & 127] = 0.f;
  __syncthreads();
  for (int u = 0; u < NU; ++u) {
    const _Float16* zxu = zx + (((size_t)d * 256 + u) * 64 + b0) * 512;
#pragma unroll
    for (int p = 0; p < 8; ++p) {
      int idx = p * 256 + tid;
      int bi = idx >> 9, cc = idx & 511;
      zs[bi][cc] = (float)zxu[(size_t)bi * 512 + cc];
    }
    __syncthreads();
    if (u > 0) {
      float2 acc[4];
#pragma unroll
      for (int bi = 0; bi < 4; ++bi) acc[bi] = make_float2(0.f, 0.f);
#pragma unroll 4
      for (int kk = 0; kk < 128; ++kk) {
        float2 w = *(const float2*)&Wh[(size_t)kk * 512 + col0];
#pragma unroll
        for (int bi = 0; bi < 4; ++bi) {
          float h = hs[bi][kk];
          acc[bi].x += w.x * h;
          acc[bi].y += w.y * h;
        }
      }
#pragma unroll
      for (int bi = 0; bi < 4; ++bi) {
        zs[bi][col0] += acc[bi].x;
        zs[bi][col0 + 1] += acc[bi].y;
      }
      __syncthreads();
    }
    int upos = d ? (NU - 1 - u) : u;
#pragma unroll
    for (int e = 0; e < 2; ++e) {
      int idx = 2 * tid + e;
      int bi = idx >> 7, j = idx & 127;
      int b = b0 + bi;
      float zi = zs[bi][j], zf = zs[bi][128 + j], zg = zs[bi][256 + j], zo = zs[bi][384 + j];
      float cp = creg[e], hp = hs[bi][j];
      float cn = sigm(zf) * cp + sigm(zi) * tanhf(zg);
      float hn = sigm(zo) * tanhf(cn);
      float mt = text_mask[upos * NB + b];
      hn = mt * hn + (1.f - mt) * hp;
      cn = mt * cn + (1.f - mt) * cp;
      creg[e] = cn;
      hs[bi][j] = hn;
      ctx[((size_t)upos * NB + b) * 256 + d * 128 + j] = hn;
    }
    __syncthreads();
  }
}

// ---------------- weight prepack: fp32 W -> split bf16 (hi+lo planes), MFMA order ----------------
__global__ __launch_bounds__(256) void k_wcvt(const float* __restrict__ w1,
                                              const float* __restrict__ wa,
                                              const float* __restrict__ w2,
                                              unsigned short* __restrict__ Wpk) {
  int ktg = blockIdx.x;
  int ntg = blockIdx.y;
  const float* W;
  int ktl;
  if (ktg < 44) { W = w1; ktl = ktg; }
  else if (ktg < 72) { W = wa; ktl = ktg - 44; }
  else { W = w2; ktl = ktg - 72; }
  int tid = threadIdx.x;
  for (int p = 0; p < 8; ++p) {
    int idx = p * 256 + tid;
    int ntl = idx >> 6, l = idx & 63;
    int nt = ntg * 32 + ntl;
    us8 vh, vl;
#pragma unroll
    for (int j = 0; j < 8; ++j) {
      float wv = W[(size_t)(ktl * 32 + (l >> 4) * 8 + j) * 2048 + nt * 16 + (l & 15)];
      unsigned short h = f2bf(wv);
      vh[j] = h;
      vl[j] = f2bf(wv - bf2f(h));
    }
    size_t o = (((size_t)ktg * 128 + nt) * 64 + l) * 8;
    *(us8*)(Wpk + o) = vh;
    *(us8*)(Wpk + WSZ + o) = vl;
  }
}

// ---------------- PERSISTENT decoder: 512 blocks (co-resident at 2/CU), targeted flags ----------
// A blocks 0..383: bg=bid/192 (32 batches), r=bid%192, c=r/16, nc=r%16.
//   slot i: c0..3 z1(i-1) [waits fbatt>=i, fbg>=i], c4..7 za(i) [fbatt>=i],
//           c8..11 z2(i-2) [fbg>=i, fbatt>=i-1]; then fa[bid]=i+1.
// B gate blocks 384..447 (batch b): wait fa(c0..3,c8..11)>=i+1; gate1(i-1)+gate2(i-2); fbg[b]=i+1.
// B att blocks 448..511 (batch b): wait fa(c4..7)>=i+1; att(i); fbatt[b]=i+1.
struct DecPp {
  const float* corr;
  const unsigned short* Wpk;
  const float *mel_mask, *text_mask, *ctx;
  const float *b_att, *b_rnn1, *b_rnn2, *w_proj, *b_proj;
  float *aw, *ak, *ah, *ac, *h1, *c1, *c2, *outs, *zerob;
  float* zX;
  unsigned *fa, *fbatt, *fbg;
};

__global__ __launch_bounds__(256, 2) void k_decP3(DecPp P) {
  __shared__ __align__(16) unsigned short xsh[32][360];
  __shared__ __align__(16) unsigned short xsl[32][360];
  int tid = threadIdx.x, bid = blockIdx.x;
  if (bid < 384) {
    // ================= A block =================
    int bg = bid / 192, r = bid % 192, c = r >> 4, nc = r & 15;
    int g, ktg0, nkt, k0;
    if (c < 4)      { g = 0; ktg0 = c * 11;            nkt = 11; k0 = c * 352; }
    else if (c < 8) { g = 1; ktg0 = 44 + (c - 4) * 7;  nkt = 7;  k0 = (c - 4) * 224; }
    else            { g = 2; ktg0 = 72 + (c - 8) * 11; nkt = 11; k0 = (c - 8) * 352; }
    int b0 = bg * 32;
    int w = tid >> 6, lane = tid & 63;
    const unsigned short* wb0 =
        P.Wpk + (((size_t)ktg0 * 128 + (size_t)(nc * 8 + w * 2)) * 64 + lane) * 8;
    int arow0 = lane & 15, acol = (lane >> 4) * 8;
    for (int i = 0; i <= NT + 1; ++i) {
      unsigned ta, tg;  // wait targets for fbatt / fbg
      if (g == 0)      { ta = (unsigned)i; tg = (unsigned)i; }
      else if (g == 1) { ta = (unsigned)i; tg = 0u; }
      else             { ta = (i > 0) ? (unsigned)(i - 1) : 0u; tg = (unsigned)i; }
      for (;;) {
        bool ok = true;
        if (tid < 32) ok = (ldU(&P.fbatt[b0 + tid]) >= ta);
        else if (tid < 64) ok = (ldU(&P.fbg[b0 + tid - 32]) >= tg);
        if (__syncthreads_and(ok)) break;
        __builtin_amdgcn_s_sleep(16);
      }
      int s = (g == 0) ? (i - 1) : (g == 1 ? i : (i - 2));
      if (s >= 0 && s < NT) {
        const float* p0 = P.corr + (size_t)s * NB * PREc;
        const float *p1, *p2, *p3;
        int s1, s2_, s3;
        if (g == 1) {
          bool z = (s == 0);
          int pp = (s - 1) & 1;
          p1 = z ? P.zerob : P.aw + (size_t)pp * NB * 256; s1 = z ? 0 : 256;
          p2 = z ? P.zerob : P.ah + (size_t)pp * NB * DECc; s2_ = z ? 0 : DECc;
          p3 = P.zerob; s3 = 0;
        } else if (g == 0) {
          int pp = s & 1;
          p1 = P.aw + (size_t)pp * NB * 256; s1 = 256;
          p2 = P.ah + (size_t)pp * NB * DECc; s2_ = DECc;
          bool z = (s == 0);
          p3 = z ? P.zerob : P.h1 + (size_t)((s - 1) & 1) * NB * DECc; s3 = z ? 0 : DECc;
        } else {
          int pp = s & 1;
          p1 = P.aw + (size_t)pp * NB * 256; s1 = 256;
          p2 = P.h1 + (size_t)pp * NB * DECc; s2_ = DECc;
          bool z = (s == 0);
          p3 = z ? P.zerob : P.outs + (size_t)(s - 1) * NB * DECc; s3 = z ? 0 : DECc;
        }
        int klen = nkt * 32;
        for (int idx = tid; idx < klen; idx += 256) {
          int k = k0 + idx;
#pragma unroll 4
          for (int bi = 0; bi < 32; ++bi) {
            int b = b0 + bi;
            float v;
            int kx = k;
            if (kx < PREc)
              v = p0[(size_t)b * PREc + kx];
            else {
              kx -= PREc;
              if (kx < 256)
                v = ldF(p1 + (size_t)b * s1 + kx);
              else {
                kx -= 256;
                if (kx < DECc)
                  v = ldF(p2 + (size_t)b * s2_ + kx);
                else
                  v = ldF(p3 + (size_t)b * s3 + (kx - DECc));
              }
            }
            unsigned short h = f2bf(v);
            xsh[bi][idx] = h;
            xsl[bi][idx] = f2bf(v - bf2f(h));
          }
        }
        __syncthreads();
        f32x4 acc[2][2];
#pragma unroll
        for (int m = 0; m < 2; ++m)
#pragma unroll
          for (int t = 0; t < 2; ++t) acc[m][t] = f32x4{0.f, 0.f, 0.f, 0.f};
        for (int kt = 0; kt < nkt; ++kt) {
          bf16x8 ah0 = *(const bf16x8*)&xsh[arow0][kt * 32 + acol];
          bf16x8 ah1 = *(const bf16x8*)&xsh[16 + arow0][kt * 32 + acol];
          bf16x8 al0 = *(const bf16x8*)&xsl[arow0][kt * 32 + acol];
          bf16x8 al1 = *(const bf16x8*)&xsl[16 + arow0][kt * 32 + acol];
          const unsigned short* wp = wb0 + (size_t)kt * 65536;
          bf16x8 b0h = *(const bf16x8*)(wp);
          bf16x8 b1h = *(const bf16x8*)(wp + 512);
          bf16x8 b0l = *(const bf16x8*)(wp + WSZ);
          bf16x8 b1l = *(const bf16x8*)(wp + WSZ + 512);
          acc[0][0] = __builtin_amdgcn_mfma_f32_16x16x32_bf16(ah0, b0h, acc[0][0], 0, 0, 0);
          acc[0][1] = __builtin_amdgcn_mfma_f32_16x16x32_bf16(ah0, b1h, acc[0][1], 0, 0, 0);
          acc[1][0] = __builtin_amdgcn_mfma_f32_16x16x32_bf16(ah1, b0h, acc[1][0], 0, 0, 0);
          acc[1][1] = __builtin_amdgcn_mfma_f32_16x16x32_bf16(ah1, b1h, acc[1][1], 0, 0, 0);
          acc[0][0] = __builtin_amdgcn_mfma_f32_16x16x32_bf16(al0, b0h, acc[0][0], 0, 0, 0);
          acc[0][1] = __builtin_amdgcn_mfma_f32_16x16x32_bf16(al0, b1h, acc[0][1], 0, 0, 0);
          acc[1][0] = __builtin_amdgcn_mfma_f32_16x16x32_bf16(al1, b0h, acc[1][0], 0, 0, 0);
          acc[1][1] = __builtin_amdgcn_mfma_f32_16x16x32_bf16(al1, b1h, acc[1][1], 0, 0, 0);
          acc[0][0] = __builtin_amdgcn_mfma_f32_16x16x32_bf16(ah0, b0l, acc[0][0], 0, 0, 0);
          acc[0][1] = __builtin_amdgcn_mfma_f32_16x16x32_bf16(ah0, b1l, acc[0][1], 0, 0, 0);
          acc[1][0] = __builtin_amdgcn_mfma_f32_16x16x32_bf16(ah1, b0l, acc[1][0], 0, 0, 0);
          acc[1][1] = __builtin_amdgcn_mfma_f32_16x16x32_bf16(ah1, b1l, acc[1][1], 0, 0, 0);
        }
#pragma unroll
        for (int m = 0; m < 2; ++m)
#pragma unroll
          for (int t = 0; t < 2; ++t) {
            int brow = b0 + m * 16 + (lane >> 4) * 4;
            int col = nc * 128 + (w * 2 + t) * 16 + (lane & 15);
            float* zb = P.zX + ((size_t)c * NB + brow) * 2048 + col;
#pragma unroll
            for (int rr = 0; rr < 4; ++rr) stF(zb + (size_t)rr * 2048, acc[m][t][rr]);
          }
      }
      __syncthreads();  // drain vmcnt: zX at L3 before flag
      if (tid == 0) stU(&P.fa[bid], (unsigned)(i + 1));
    }
    return;
  }
  // ================= B blocks =================
  int wb = bid - 384;
  if (wb < 64) {  // gates block, batch b: gate1(i-1) + gate2(i-2)
    int b = wb;
    int bg = b >> 5;
    for (int i = 0; i <= NT + 1; ++i) {
      for (;;) {
        bool ok = true;
        if (tid < 128) {
          int idx = tid >> 4;
          int cc = (idx < 4) ? idx : (idx + 4);  // c 0..3 and 8..11
          ok = (ldU(&P.fa[bg * 192 + cc * 16 + (tid & 15)]) >= (unsigned)(i + 1));
        }
        if (__syncthreads_and(ok)) break;
        __builtin_amdgcn_s_sleep(16);
      }
      int j = 2 * tid;
      {  // gate1, s = i-1
        int s = i - 1;
        if (s >= 0 && s < NT) {
          bool z = (s == 0);
          const float* cprev = z ? P.zerob : P.c1 + (size_t)((s - 1) & 1) * NB * 512;
          const float* hprev = z ? P.zerob : P.h1 + (size_t)((s - 1) & 1) * NB * 512;
          float2 zi = *(const float2*)(P.b_rnn1 + j);
          float2 zf = *(const float2*)(P.b_rnn1 + 512 + j);
          float2 zg = *(const float2*)(P.b_rnn1 + 1024 + j);
          float2 zo = *(const float2*)(P.b_rnn1 + 1536 + j);
          for (int cc = 0; cc <= 3; ++cc) {
            const float* q = P.zX + ((size_t)cc * NB + b) * 2048 + j;
            float2 a = ldF2(q), f2 = ldF2(q + 512), g2 = ldF2(q + 1024), o2 = ldF2(q + 1536);
            zi.x += a.x; zi.y += a.y;
            zf.x += f2.x; zf.y += f2.y;
            zg.x += g2.x; zg.y += g2.y;
            zo.x += o2.x; zo.y += o2.y;
          }
          float2 cp = z ? make_float2(0.f, 0.f) : ldF2(cprev + (size_t)b * 512 + j);
          float2 hp = z ? make_float2(0.f, 0.f) : ldF2(hprev + (size_t)b * 512 + j);
          float m = P.mel_mask[(size_t)s * NB + b];
          float cnx = sigm(zf.x) * cp.x + sigm(zi.x) * tanhf(zg.x);
          float cny = sigm(zf.y) * cp.y + sigm(zi.y) * tanhf(zg.y);
          float hnx = sigm(zo.x) * tanhf(cnx);
          float hny = sigm(zo.y) * tanhf(cny);
          stF2(P.h1 + (size_t)(s & 1) * NB * 512 + (size_t)b * 512 + j,
               make_float2(m * hnx + (1.f - m) * hp.x, m * hny + (1.f - m) * hp.y));
          stF2(P.c1 + (size_t)(s & 1) * NB * 512 + (size_t)b * 512 + j,
               make_float2(m * cnx + (1.f - m) * cp.x, m * cny + (1.f - m) * cp.y));
        }
      }
      {  // gate2, s = i-2
        int s = i - 2;
        if (s >= 0 && s < NT) {
          bool z = (s == 0);
          const float* cprev = z ? P.zerob : P.c2 + (size_t)((s - 1) & 1) * NB * 512;
          const float* hprev = z ? P.zerob : P.outs + (size_t)(s - 1) * NB * 512;
          float2 zi = *(const float2*)(P.b_rnn2 + j);
          float2 zf = *(const float2*)(P.b_rnn2 + 512 + j);
          float2 zg = *(const float2*)(P.b_rnn2 + 1024 + j);
          float2 zo = *(const float2*)(P.b_rnn2 + 1536 + j);
          for (int cc = 8; cc <= 11; ++cc) {
            const float* q = P.zX + ((size_t)cc * NB + b) * 2048 + j;
            float2 a = ldF2(q), f2 = ldF2(q + 512), g2 = ldF2(q + 1024), o2 = ldF2(q + 1536);
            zi.x += a.x; zi.y += a.y;
            zf.x += f2.x; zf.y += f2.y;
            zg.x += g2.x; zg.y += g2.y;
            zo.x += o2.x; zo.y += o2.y;
          }
          float2 cp = z ? make_float2(0.f, 0.f) : ldF2(cprev + (size_t)b * 512 + j);
          float2 hp = z ? make_float2(0.f, 0.f) : ldF2(hprev + (size_t)b * 512 + j);
          float m = P.mel_mask[(size_t)s * NB + b];
          float cnx = sigm(zf.x) * cp.x + sigm(zi.x) * tanhf(zg.x);
          float cny = sigm(zf.y) * cp.y + sigm(zi.y) * tanhf(zg.y);
          float hnx = sigm(zo.x) * tanhf(cnx);
          float hny = sigm(zo.y) * tanhf(cny);
          stF2(P.outs + (size_t)s * NB * 512 + (size_t)b * 512 + j,
               make_float2(m * hnx + (1.f - m) * hp.x, m * hny + (1.f - m) * hp.y));
          stF2(P.c2 + (size_t)(s & 1) * NB * 512 + (size_t)b * 512 + j,
               make_float2(m * cnx + (1.f - m) * cp.x, m * cny + (1.f - m) * cp.y));
        }
      }
      __syncthreads();
      if (tid == 0) stU(&P.fbg[b], (unsigned)(i + 1));
    }
    return;
  }
  // att block, batch b
  int b = wb - 64;
  int bg = b >> 5;
  float* sh = (float*)&xsh[0][0];
  for (int i = 0; i <= NT + 1; ++i) {
    for (;;) {
      bool ok = true;
      if (tid < 64)
        ok = (ldU(&P.fa[bg * 192 + (4 + (tid >> 4)) * 16 + (tid & 15)]) >= (unsigned)(i + 1));
      if (__syncthreads_and(ok)) break;
      __builtin_amdgcn_s_sleep(16);
    }
    int s = i;
    if (s < NT) {
      float* ah_s = sh;
      float* red_s = sh + 512;
      float* pr_s = sh + 768;
      float* abk = sh + 800;
      float* phi_s = sh + 896;
      float m = P.mel_mask[(size_t)s * NB + b];
      bool z = (s == 0);
      int pp = (s - 1) & 1;
      {
        int j = 2 * tid;
        float2 zi = *(const float2*)(P.b_att + j);
        float2 zf = *(const float2*)(P.b_att + 512 + j);
        float2 zg = *(const float2*)(P.b_att + 1024 + j);
        float2 zo = *(const float2*)(P.b_att + 1536 + j);
        for (int cc = 4; cc <= 7; ++cc) {
          const float* q = P.zX + ((size_t)cc * NB + b) * 2048 + j;
          float2 a = ldF2(q), f2 = ldF2(q + 512), g2 = ldF2(q + 1024), o2 = ldF2(q + 1536);
          zi.x += a.x; zi.y += a.y;
          zf.x += f2.x; zf.y += f2.y;
          zg.x += g2.x; zg.y += g2.y;
          zo.x += o2.x; zo.y += o2.y;
        }
        float2 cp = z ? make_float2(0.f, 0.f)
                      : ldF2(P.ac + (size_t)pp * NB * 512 + (size_t)b * 512 + j);
        float2 hp = z ? make_float2(0.f, 0.f)
                      : ldF2(P.ah + (size_t)pp * NB * 512 + (size_t)b * 512 + j);
        float cnx = sigm(zf.x) * cp.x + sigm(zi.x) * tanhf(zg.x);
        float cny = sigm(zf.y) * cp.y + sigm(zi.y) * tanhf(zg.y);
        float hrx = sigm(zo.x) * tanhf(cnx);
        float hry = sigm(zo.y) * tanhf(cny);
        ah_s[j] = hrx;
        ah_s[j + 1] = hry;
        stF2(P.ah + (size_t)(s & 1) * NB * 512 + (size_t)b * 512 + j,
             make_float2(m * hrx + (1.f - m) * hp.x, m * hry + (1.f - m) * hp.y));
        stF2(P.ac + (size_t)(s & 1) * NB * 512 + (size_t)b * 512 + j,
             make_float2(m * cnx + (1.f - m) * cp.x, m * cny + (1.f - m) * cp.y));
      }
      __syncthreads();
      {
        int cc2 = tid & 31, ch = tid >> 5;
        float ssum = 0.f;
        if (cc2 < 30)
          for (int k = ch * 64; k < ch * 64 + 64; ++k) ssum += ah_s[k] * P.w_proj[k * 30 + cc2];
        red_s[ch * 32 + cc2] = ssum;
      }
      __syncthreads();
      if (tid < 30) {
        float ssum = P.b_proj[tid];
        for (int ch = 0; ch < 8; ++ch) ssum += red_s[ch * 32 + tid];
        pr_s[tid] = ssum;
      }
      __syncthreads();
      if (tid < WMc) {
        float kp = z ? 0.f : ldF(P.ak + (size_t)pp * NB * AKS + (size_t)b * AKS + tid);
        float a_t = softplusf(pr_s[tid]);
        float b_t = softplusf(pr_s[WMc + tid]);
        float k_t = kp + softplusf(pr_s[2 * WMc + tid]);
        abk[tid] = a_t;
        abk[32 + tid] = b_t;
        abk[64 + tid] = k_t;
        stF(P.ak + (size_t)(s & 1) * NB * AKS + (size_t)b * AKS + tid, m * k_t + (1.f - m) * kp);
      }
      __syncthreads();
      {
        int u = tid;
        float ssum = 0.f;
#pragma unroll
        for (int gg = 0; gg < WMc; ++gg) {
          float dd = abk[64 + gg] - (float)u;
          ssum += abk[gg] * expf(-abk[32 + gg] * dd * dd);
        }
        phi_s[u] = ssum * P.text_mask[u * NB + b];
      }
      __syncthreads();
      {
        int dcol = tid;
        float ssum = 0.f;
#pragma unroll 8
        for (int u = 0; u < NU; ++u)
          ssum += phi_s[u] * __builtin_nontemporal_load(P.ctx + ((size_t)u * NB + b) * 256 + dcol);
        float wprev = z ? 0.f : ldF(P.aw + (size_t)pp * NB * 256 + (size_t)b * 256 + dcol);
        stF(P.aw + (size_t)(s & 1) * NB * 256 + (size_t)b * 256 + dcol,
            m * ssum + (1.f - m) * wprev);
      }
    }
    __syncthreads();
    if (tid == 0) stU(&P.fbatt[b], (unsigned)(i + 1));
  }
}

// =====================================================================================
extern "C" void kernel_launch(void* const* d_in, const int* in_sizes, int n_in,
                              void* d_out, int out_size, void* d_ws, size_t ws_size,
                              hipStream_t stream) {
  const float* in_mels = (const float*)d_in[0];
  const float* mel_mask = (const float*)d_in[1];
  const int* text = (const int*)d_in[2];
  const float* text_mask = (const float*)d_in[3];
  const float* w_pre1 = (const float*)d_in[4];
  const float* b_pre1 = (const float*)d_in[5];
  const float* w_pre2 = (const float*)d_in[6];
  const float* b_pre2 = (const float*)d_in[7];
  const float* emb = (const float*)d_in[8];
  const float* conv_w0 = (const float*)d_in[9];
  const float* conv_b0 = (const float*)d_in[10];
  const float* conv_w1 = (const float*)d_in[11];
  const float* conv_b1 = (const float*)d_in[12];
  const float* conv_w2 = (const float*)d_in[13];
  const float* conv_b2 = (const float*)d_in[14];
  const float* w_bif = (const float*)d_in[15];
  const float* b_bif = (const float*)d_in[16];
  const float* w_bib = (const float*)d_in[17];
  const float* b_bib = (const float*)d_in[18];
  const float* w_att = (const float*)d_in[19];
  const float* b_att = (const float*)d_in[20];
  const float* w_proj = (const float*)d_in[21];
  const float* b_proj = (const float*)d_in[22];
  const float* w_rnn1 = (const float*)d_in[23];
  const float* b_rnn1 = (const float*)d_in[24];
  const float* w_rnn2 = (const float*)d_in[25];
  const float* b_rnn2 = (const float*)d_in[26];
  const float* w_outp = (const float*)d_in[27];
  const float* b_outp = (const float*)d_in[28];

  float* ws = (float*)d_ws;
  size_t off = 0;
  auto alloc = [&](size_t n) {
    float* p = ws + off;
    off += (n + 63) & ~(size_t)63;
    return p;
  };
  float* corr = alloc((size_t)NT * NB * PREc);
  float* embx = alloc((size_t)NB * NU * EMBc);
  float* wpkR = alloc(WSZ);  // hi+lo planes (30.4MB); also prenet tmp / conv ping
  float* zX = alloc((size_t)12 * NB * 2048);
  float* ctx = alloc((size_t)NU * NB * 2 * ENCc);  // also conv pong
  float* convbuf = alloc((size_t)NB * NU * NFc);
  float* aw = alloc((size_t)2 * NB * 2 * ENCc);
  float* ak = alloc((size_t)2 * NB * AKS);
  float* ah = alloc((size_t)2 * NB * DECc);
  float* ac = alloc((size_t)2 * NB * DECc);
  float* h1 = alloc((size_t)2 * NB * DECc);
  float* c1 = alloc((size_t)2 * NB * DECc);
  float* c2 = alloc((size_t)2 * NB * DECc);
  float* outs = alloc((size_t)NT * NB * DECc);  // h2 rows; encoder zx (fp16) overlays
  float* weff0 = alloc((size_t)5 * EMBc * NFc);
  float* beff0 = alloc(NFc);
  float* weff1 = alloc((size_t)5 * NFc * NFc);
  float* beff1 = alloc(NFc);
  float* weff2 = alloc((size_t)5 * NFc * NFc);
  float* beff2 = alloc(NFc);
  float* zerob = alloc(1024);
  float* flagsf = alloc(1024);
  unsigned* fa = (unsigned*)flagsf;   // 384
  unsigned* fbatt = fa + 448;         // 64
  unsigned* fbg = fa + 512;           // 64

  unsigned short* Wpk = (unsigned short*)wpkR;
  _Float16* zx = (_Float16*)outs;
  float* tmp = wpkR;
  float* convA = wpkR;
  float* convB = ctx;

  hipMemsetAsync(zerob, 0, 1024 * sizeof(float), stream);
  hipMemsetAsync(flagsf, 0, 1024 * sizeof(float), stream);

  // ---- prenet ----
  k_dense<NMELc, PREc, 8><<<NT * NB / 8, 128, 0, stream>>>(in_mels, w_pre1, b_pre1, tmp, NT * NB);
  k_dense<PREc, PREc, 8><<<NT * NB / 8, 128, 0, stream>>>(tmp, w_pre2, b_pre2, corr, NT * NB);

  // ---- text conv stacks ----
  k_embed<<<(NB * NU * EMBc + 255) / 256, 256, 0, stream>>>(text, emb, embx);
  k_weff<EMBc><<<(5 * EMBc * NFc + 255) / 256, 256, 0, stream>>>(conv_w0, conv_b0, weff0, beff0);
  k_weff<NFc><<<(5 * NFc * NFc + 255) / 256, 256, 0, stream>>>(conv_w1, conv_b1, weff1, beff1);
  k_weff<NFc><<<(5 * NFc * NFc + 255) / 256, 256, 0, stream>>>(conv_w2, conv_b2, weff2, beff2);
  k_conv<EMBc, false><<<dim3(NU / 8, NB), 128, 0, stream>>>(embx, weff0, beff0, convB);
  k_conv<NFc, true><<<dim3(NU / 8, NB), 128, 0, stream>>>(convB, weff1, beff1, convA);
  k_conv<NFc, true><<<dim3(NU / 8, NB), 128, 0, stream>>>(convA, weff2, beff2, convbuf);

  // ---- prepack decoder weights ----
  k_wcvt<<<dim3(116, 4), 256, 0, stream>>>(w_rnn1, w_att, w_rnn2, Wpk);

  // ---- encoder ----
  k_zx<<<dim3(512, 8), 512, 0, stream>>>(w_bif, b_bif, w_bib, b_bib, convbuf, zx);
  k_encP2<<<32, 256, 0, stream>>>(w_bif, w_bib, zx, text_mask, ctx);

  // ---- persistent decoder (single launch, 512 blocks = guaranteed co-resident) ----
  DecPp D;
  D.corr = corr; D.Wpk = Wpk;
  D.mel_mask = mel_mask; D.text_mask = text_mask; D.ctx = ctx;
  D.b_att = b_att; D.b_rnn1 = b_rnn1; D.b_rnn2 = b_rnn2;
  D.w_proj = w_proj; D.b_proj = b_proj;
  D.aw = aw; D.ak = ak; D.ah = ah; D.ac = ac;
  D.h1 = h1; D.c1 = c1; D.c2 = c2; D.outs = outs; D.zerob = zerob;
  D.zX = zX;
  D.fa = fa; D.fbatt = fbatt; D.fbg = fbg;
  k_decP3<<<512, 256, 0, stream>>>(D);

  // ---- output projection ----
  k_dense<DECc, NMELc, 8><<<NT * NB / 8, 128, 0, stream>>>(outs, w_outp, b_outp, (float*)d_out,
                                                           NT * NB);
}

// Round 16
// 12848.055 us; speedup vs baseline: 1.3823x; 1.3823x over previous
//
#include <hip/hip_runtime.h>
#include <math.h>

constexpr int NB    = 64;
constexpr int NT    = 256;
constexpr int NU    = 256;
constexpr int NMELc = 80;
constexpr int PREc  = 128;
constexpr int EMBc  = 15;
constexpr int NFc   = 128;
constexpr int ENCc  = 128;
constexpr int DECc  = 512;
constexpr int WMc   = 10;
constexpr int AKS   = 16;
constexpr size_t WSZ = (size_t)116 * 128 * 512;  // ushorts per weight plane (hi or lo)

using bf16x8 = __attribute__((ext_vector_type(8))) short;
using us8    = __attribute__((ext_vector_type(8))) unsigned short;
using f32x4  = __attribute__((ext_vector_type(4))) float;

__device__ __forceinline__ float sigm(float x) { return 1.0f / (1.0f + expf(-x)); }
__device__ __forceinline__ float softplusf(float x) { return fmaxf(x, 0.0f) + log1pf(expf(-fabsf(x))); }
__device__ __forceinline__ unsigned short f2bf(float f) {
  unsigned u = __builtin_bit_cast(unsigned, f);
  return (unsigned short)((u + 0x7FFFu + ((u >> 16) & 1u)) >> 16);
}
__device__ __forceinline__ float bf2f(unsigned short h) {
  return __builtin_bit_cast(float, (unsigned)h << 16);
}
// agent-relaxed bypass accessors (cross-XCD visible at L3, no cache maintenance)
__device__ __forceinline__ float ldF(const float* p) {
  return __hip_atomic_load(p, __ATOMIC_RELAXED, __HIP_MEMORY_SCOPE_AGENT);
}
__device__ __forceinline__ void stF(float* p, float v) {
  __hip_atomic_store(p, v, __ATOMIC_RELAXED, __HIP_MEMORY_SCOPE_AGENT);
}
__device__ __forceinline__ float2 ldF2(const float* p) {
  unsigned long long u = __hip_atomic_load((const unsigned long long*)p, __ATOMIC_RELAXED,
                                           __HIP_MEMORY_SCOPE_AGENT);
  return __builtin_bit_cast(float2, u);
}
__device__ __forceinline__ unsigned ldU(const unsigned* p) {
  return __hip_atomic_load(p, __ATOMIC_RELAXED, __HIP_MEMORY_SCOPE_AGENT);
}
__device__ __forceinline__ void stU(unsigned* p, unsigned v) {
  __hip_atomic_store(p, v, __ATOMIC_RELAXED, __HIP_MEMORY_SCOPE_AGENT);
}

// ---------------- generic dense ----------------
template <int K, int N, int RB>
__global__ void k_dense(const float* __restrict__ X, const float* __restrict__ W,
                        const float* __restrict__ bias, float* __restrict__ Y, int R) {
  __shared__ float xs[RB][K];
  int r0 = blockIdx.x * RB;
  int tid = threadIdx.x;  // 128
  for (int idx = tid; idx < RB * K; idx += 128) {
    int r = idx / K, k = idx % K;
    xs[r][k] = (r0 + r < R) ? X[(size_t)(r0 + r) * K + k] : 0.0f;
  }
  __syncthreads();
  int j = tid;
  if (j >= N) return;
  float acc[RB];
#pragma unroll
  for (int r = 0; r < RB; ++r) acc[r] = 0.f;
  for (int k = 0; k < K; ++k) {
    float w = W[(size_t)k * N + j];
#pragma unroll
    for (int r = 0; r < RB; ++r) acc[r] += xs[r][k] * w;
  }
  float bj = bias[j];
  for (int r = 0; r < RB; ++r)
    if (r0 + r < R) Y[(size_t)(r0 + r) * N + j] = acc[r] + bj;
}

// ---------------- embedding gather ----------------
__global__ void k_embed(const int* __restrict__ text, const float* __restrict__ emb,
                        float* __restrict__ out) {
  int idx = blockIdx.x * blockDim.x + threadIdx.x;
  if (idx >= NB * NU * EMBc) return;
  int c = idx % EMBc;
  int bu = idx / EMBc;
  int u = bu % NU, b = bu / NU;
  out[idx] = emb[text[u * NB + b] * EMBc + c];
}

// ---------------- merged conv weights ----------------
template <int CIN>
__global__ void k_weff(const float* __restrict__ w, const float* __restrict__ bb,
                       float* __restrict__ weff, float* __restrict__ beff) {
  int idx = blockIdx.x * blockDim.x + threadIdx.x;
  const int tot = 5 * CIN * NFc;
  if (idx < tot) {
    int f = idx % NFc;
    int tc = idx / NFc;
    int c = tc % CIN, t = tc / CIN;
    float m0 = (t == 2) ? 1.f : 0.f;
    float m1 = (t >= 1 && t <= 3) ? 1.f : 0.f;
    float w0 = w[((size_t)(0 * 5 + t) * CIN + c) * NFc + f];
    float w1 = w[((size_t)(1 * 5 + t) * CIN + c) * NFc + f];
    float w2 = w[((size_t)(2 * 5 + t) * CIN + c) * NFc + f];
    weff[idx] = w0 * m0 + w1 * m1 + w2;
  }
  if (idx < NFc) beff[idx] = bb[idx] + bb[NFc + idx] + bb[2 * NFc + idx];
}

// ---------------- conv stack ----------------
template <int CIN, bool RES>
__global__ void k_conv(const float* __restrict__ x, const float* __restrict__ weff,
                       const float* __restrict__ beff, float* __restrict__ y) {
  const int UT = 8;
  __shared__ float xs[(UT + 4) * CIN];
  int b = blockIdx.y, u0 = blockIdx.x * UT;
  int tid = threadIdx.x;  // 128
  for (int idx = tid; idx < (UT + 4) * CIN; idx += 128) {
    int c = idx % CIN;
    int uu = idx / CIN;
    int u = u0 + uu - 2;
    xs[idx] = (u >= 0 && u < NU) ? x[((size_t)b * NU + u) * CIN + c] : 0.f;
  }
  __syncthreads();
  int f = tid;
  float acc[UT];
#pragma unroll
  for (int r = 0; r < UT; ++r) acc[r] = beff[f];
  for (int t = 0; t < 5; ++t)
    for (int c = 0; c < CIN; ++c) {
      float w = weff[((size_t)t * CIN + c) * NFc + f];
#pragma unroll
      for (int r = 0; r < UT; ++r) acc[r] += xs[(r + t) * CIN + c] * w;
    }
  for (int r = 0; r < UT; ++r) {
    float v = fmaxf(acc[r], 0.f);
    if (RES) v += xs[(r + 2) * CIN + f];
    y[((size_t)b * NU + u0 + r) * NFc + f] = v;
  }
}

// ---------------- encoder x-part precompute: zx[d][u][b][512] = conv @ Wx + bias (fp16) ----
__global__ __launch_bounds__(512) void k_zx(const float* __restrict__ Wf,
                                            const float* __restrict__ bf,
                                            const float* __restrict__ Wb,
                                            const float* __restrict__ bb_,
                                            const float* __restrict__ convt,
                                            _Float16* __restrict__ zx) {
  __shared__ float xs[8][128];
  int du = blockIdx.x;
  int d = du >> 8, u = du & 255;
  int bg = blockIdx.y;  // 8 batches
  const float* Wd = d ? Wb : Wf;
  const float* bd = d ? bb_ : bf;
  int upos_x = d ? (NU - 1 - u) : u;
  int tid = threadIdx.x;
  for (int idx = tid; idx < 8 * 128; idx += 512) {
    int bi = idx >> 7, k = idx & 127;
    xs[bi][k] = convt[((size_t)(bg * 8 + bi) * NU + upos_x) * 128 + k];
  }
  __syncthreads();
  int j = tid;  // 512 cols
  float acc[8];
#pragma unroll
  for (int r = 0; r < 8; ++r) acc[r] = 0.f;
  for (int k = 0; k < 128; ++k) {
    float w = Wd[(size_t)k * 512 + j];
#pragma unroll
    for (int r = 0; r < 8; ++r) acc[r] += xs[r][k] * w;
  }
  float bj = bd[j];
#pragma unroll
  for (int r = 0; r < 8; ++r)
    zx[(((size_t)d * 256 + u) * 64 + bg * 8 + r) * 512 + j] = (_Float16)(acc[r] + bj);
}

// ---------------- persistent encoder: 32 blocks (g16 x d2), block-local chains ----------------
__global__ __launch_bounds__(256) void k_encP2(const float* __restrict__ Wf,
                                               const float* __restrict__ Wb,
                                               const _Float16* __restrict__ zx,
                                               const float* __restrict__ text_mask,
                                               float* __restrict__ ctx) {
  __shared__ float hs[4][128];
  __shared__ float zs[4][512];
  int bid = blockIdx.x;
  int d = bid & 1, g = bid >> 1;
  int b0 = g * 4;
  const float* Wh = (d ? Wb : Wf) + (size_t)128 * 512;  // h-part rows
  int tid = threadIdx.x;
  int q = tid >> 6, lane = tid & 63;
  int col0 = q * 128 + 2 * lane;
  float creg[2] = {0.f, 0.f};
  for (int idx = tid; idx < 512; idx += 256) hs[idx >> 7][idx & 127] = 0.f;
  __syncthreads();
  for (int u = 0; u < NU; ++u) {
    const _Float16* zxu = zx + (((size_t)d * 256 + u) * 64 + b0) * 512;
#pragma unroll
    for (int p = 0; p < 8; ++p) {
      int idx = p * 256 + tid;
      int bi = idx >> 9, cc = idx & 511;
      zs[bi][cc] = (float)zxu[(size_t)bi * 512 + cc];
    }
    __syncthreads();
    if (u > 0) {
      float2 acc[4];
#pragma unroll
      for (int bi = 0; bi < 4; ++bi) acc[bi] = make_float2(0.f, 0.f);
#pragma unroll 4
      for (int kk = 0; kk < 128; ++kk) {
        float2 w = *(const float2*)&Wh[(size_t)kk * 512 + col0];
#pragma unroll
        for (int bi = 0; bi < 4; ++bi) {
          float h = hs[bi][kk];
          acc[bi].x += w.x * h;
          acc[bi].y += w.y * h;
        }
      }
#pragma unroll
      for (int bi = 0; bi < 4; ++bi) {
        zs[bi][col0] += acc[bi].x;
        zs[bi][col0 + 1] += acc[bi].y;
      }
      __syncthreads();
    }
    int upos = d ? (NU - 1 - u) : u;
#pragma unroll
    for (int e = 0; e < 2; ++e) {
      int idx = 2 * tid + e;
      int bi = idx >> 7, j = idx & 127;
      int b = b0 + bi;
      float zi = zs[bi][j], zf = zs[bi][128 + j], zg = zs[bi][256 + j], zo = zs[bi][384 + j];
      float cp = creg[e], hp = hs[bi][j];
      float cn = sigm(zf) * cp + sigm(zi) * tanhf(zg);
      float hn = sigm(zo) * tanhf(cn);
      float mt = text_mask[upos * NB + b];
      hn = mt * hn + (1.f - mt) * hp;
      cn = mt * cn + (1.f - mt) * cp;
      creg[e] = cn;
      hs[bi][j] = hn;
      ctx[((size_t)upos * NB + b) * 256 + d * 128 + j] = hn;
    }
    __syncthreads();
  }
}

// ---------------- weight prepack: fp32 W -> split bf16 (hi+lo planes), MFMA order ----------------
__global__ __launch_bounds__(256) void k_wcvt(const float* __restrict__ w1,
                                              const float* __restrict__ wa,
                                              const float* __restrict__ w2,
                                              unsigned short* __restrict__ Wpk) {
  int ktg = blockIdx.x;  // 0..115
  int ntg = blockIdx.y;  // 0..3
  const float* W;
  int ktl;
  if (ktg < 44) { W = w1; ktl = ktg; }
  else if (ktg < 72) { W = wa; ktl = ktg - 44; }
  else { W = w2; ktl = ktg - 72; }
  int tid = threadIdx.x;
  for (int p = 0; p < 8; ++p) {
    int idx = p * 256 + tid;  // ntl(32) x lane(64)
    int ntl = idx >> 6, l = idx & 63;
    int nt = ntg * 32 + ntl;
    us8 vh, vl;
#pragma unroll
    for (int j = 0; j < 8; ++j) {
      float wv = W[(size_t)(ktl * 32 + (l >> 4) * 8 + j) * 2048 + nt * 16 + (l & 15)];
      unsigned short h = f2bf(wv);
      vh[j] = h;
      vl[j] = f2bf(wv - bf2f(h));
    }
    size_t o = (((size_t)ktg * 128 + nt) * 64 + l) * 8;
    *(us8*)(Wpk + o) = vh;
    *(us8*)(Wpk + WSZ + o) = vl;
  }
}

// ---------------- merged decoder step: A (3 GEMMs) + B (gates+att) in ONE launch ----------------
// A: 384 blocks: bg = bid/192 (32 batches), r = bid%192, c = r/16, nc = r%16 (128 cols).
//    chunks: c 0..3 z1(i-1) [ktg0=c*11], c 4..7 za(i) [44+(c-4)*7], c 8..11 z2(i-2) [72+(c-8)*11].
//    zX[c][b][2048] written via agent-bypass stores; flag[bid] = i+1 after syncthreads drain.
//    kt-loop W tiles are software-pipelined (double-buffered in regs) to deepen streaming.
// B: 192 blocks (bid >= 384): 64 gate1(i-1) [polls flags c0..3], 64 gate2(i-2) [c8..11],
//    64 att(i) [c4..7]; zX read via agent-bypass loads.
struct DecMp {
  const float* corr;
  const unsigned short* Wpk;
  const float *mel_mask, *text_mask, *ctx;
  const float *b_att, *b_rnn1, *b_rnn2, *w_proj, *b_proj;
  float *aw, *ak, *ah, *ac, *h1, *c1, *c2, *outs, *zerob;
  float* zX;
  unsigned* flags;
};

__device__ __forceinline__ void wait_flags(const unsigned* flags, int base, unsigned target) {
  int tid = threadIdx.x;
  for (;;) {
    bool ok = true;
    if (tid < 128) {
      int f = (tid < 64) ? (base + tid) : (192 + base + (tid - 64));
      ok = (ldU(&flags[f]) >= target);
    }
    if (__syncthreads_and(ok)) break;
    __builtin_amdgcn_s_sleep(8);
  }
}

__device__ __forceinline__ void do_gateM(const float* zX, int clo, int chi, const float* bias,
                                         const float* cprev, const float* hprev, bool zfirst,
                                         const float* mm, float* hout, float* cout, int b, int j) {
  float2 zi = *(const float2*)(bias + j);
  float2 zf = *(const float2*)(bias + 512 + j);
  float2 zg = *(const float2*)(bias + 1024 + j);
  float2 zo = *(const float2*)(bias + 1536 + j);
  for (int c = clo; c <= chi; ++c) {
    const float* q = zX + ((size_t)c * NB + b) * 2048 + j;
    float2 a = ldF2(q), f2 = ldF2(q + 512), g2 = ldF2(q + 1024), o2 = ldF2(q + 1536);
    zi.x += a.x; zi.y += a.y;
    zf.x += f2.x; zf.y += f2.y;
    zg.x += g2.x; zg.y += g2.y;
    zo.x += o2.x; zo.y += o2.y;
  }
  float2 cp = zfirst ? make_float2(0.f, 0.f) : *(const float2*)(cprev + (size_t)b * 512 + j);
  float2 hp = zfirst ? make_float2(0.f, 0.f) : *(const float2*)(hprev + (size_t)b * 512 + j);
  float m = mm[b];
  float cnx = sigm(zf.x) * cp.x + sigm(zi.x) * tanhf(zg.x);
  float cny = sigm(zf.y) * cp.y + sigm(zi.y) * tanhf(zg.y);
  float hnx = sigm(zo.x) * tanhf(cnx);
  float hny = sigm(zo.y) * tanhf(cny);
  *(float2*)(hout + (size_t)b * 512 + j) =
      make_float2(m * hnx + (1.f - m) * hp.x, m * hny + (1.f - m) * hp.y);
  *(float2*)(cout + (size_t)b * 512 + j) =
      make_float2(m * cnx + (1.f - m) * cp.x, m * cny + (1.f - m) * cp.y);
}

__global__ __launch_bounds__(256) void k_decM(DecMp P, int i) {
  __shared__ __align__(16) unsigned short xsh[32][360];
  __shared__ __align__(16) unsigned short xsl[32][360];
  int tid = threadIdx.x, bid = blockIdx.x;
  if (bid < 384) {
    // ================= A part =================
    int bg = bid / 192, r = bid % 192, c = r >> 4, nc = r & 15;
    int g, ktg0, nkt, k0;
    if (c < 4)      { g = 0; ktg0 = c * 11;            nkt = 11; k0 = c * 352; }
    else if (c < 8) { g = 1; ktg0 = 44 + (c - 4) * 7;  nkt = 7;  k0 = (c - 4) * 224; }
    else            { g = 2; ktg0 = 72 + (c - 8) * 11; nkt = 11; k0 = (c - 8) * 352; }
    int s = (g == 0) ? (i - 1) : (g == 1 ? i : (i - 2));
    if (s >= 0 && s < NT) {
      const float* p0 = P.corr + (size_t)s * NB * PREc;
      const float *p1, *p2, *p3;
      int s1, s2_, s3;
      if (g == 1) {
        bool z = (s == 0);
        int pp = (s - 1) & 1;
        p1 = z ? P.zerob : P.aw + (size_t)pp * NB * 256; s1 = z ? 0 : 256;
        p2 = z ? P.zerob : P.ah + (size_t)pp * NB * DECc; s2_ = z ? 0 : DECc;
        p3 = P.zerob; s3 = 0;
      } else if (g == 0) {
        int pp = s & 1;
        p1 = P.aw + (size_t)pp * NB * 256; s1 = 256;
        p2 = P.ah + (size_t)pp * NB * DECc; s2_ = DECc;
        bool z = (s == 0);
        p3 = z ? P.zerob : P.h1 + (size_t)((s - 1) & 1) * NB * DECc; s3 = z ? 0 : DECc;
      } else {
        int pp = s & 1;
        p1 = P.aw + (size_t)pp * NB * 256; s1 = 256;
        p2 = P.h1 + (size_t)pp * NB * DECc; s2_ = DECc;
        bool z = (s == 0);
        p3 = z ? P.zerob : P.outs + (size_t)(s - 1) * NB * DECc; s3 = z ? 0 : DECc;
      }
      int klen = nkt * 32;
      for (int idx = tid; idx < klen; idx += 256) {
        int k = k0 + idx;
#pragma unroll 4
        for (int bi = 0; bi < 32; ++bi) {
          int b = bg * 32 + bi;
          float v;
          int kx = k;
          if (kx < PREc)
            v = p0[(size_t)b * PREc + kx];
          else {
            kx -= PREc;
            if (kx < 256)
              v = p1[(size_t)b * s1 + kx];
            else {
              kx -= 256;
              if (kx < DECc)
                v = p2[(size_t)b * s2_ + kx];
              else
                v = p3[(size_t)b * s3 + (kx - DECc)];
            }
          }
          unsigned short h = f2bf(v);
          xsh[bi][idx] = h;
          xsl[bi][idx] = f2bf(v - bf2f(h));
        }
      }
      __syncthreads();
      int w = tid >> 6, lane = tid & 63;
      const unsigned short* wb0 =
          P.Wpk + (((size_t)ktg0 * 128 + (size_t)(nc * 8 + w * 2)) * 64 + lane) * 8;
      f32x4 acc[2][2];
#pragma unroll
      for (int m = 0; m < 2; ++m)
#pragma unroll
        for (int t = 0; t < 2; ++t) acc[m][t] = f32x4{0.f, 0.f, 0.f, 0.f};
      int arow0 = lane & 15, acol = (lane >> 4) * 8;
      // software-pipelined W tiles: prefetch kt+1 while computing kt
      bf16x8 cb0h = *(const bf16x8*)(wb0);
      bf16x8 cb1h = *(const bf16x8*)(wb0 + 512);
      bf16x8 cb0l = *(const bf16x8*)(wb0 + WSZ);
      bf16x8 cb1l = *(const bf16x8*)(wb0 + WSZ + 512);
      for (int kt = 0; kt < nkt; ++kt) {
        const unsigned short* wpn = wb0 + (size_t)(kt + 1) * 65536;  // may overshoot into zX: unused
        bf16x8 nb0h = *(const bf16x8*)(wpn);
        bf16x8 nb1h = *(const bf16x8*)(wpn + 512);
        bf16x8 nb0l = *(const bf16x8*)(wpn + WSZ);
        bf16x8 nb1l = *(const bf16x8*)(wpn + WSZ + 512);
        bf16x8 ah0 = *(const bf16x8*)&xsh[arow0][kt * 32 + acol];
        bf16x8 ah1 = *(const bf16x8*)&xsh[16 + arow0][kt * 32 + acol];
        bf16x8 al0 = *(const bf16x8*)&xsl[arow0][kt * 32 + acol];
        bf16x8 al1 = *(const bf16x8*)&xsl[16 + arow0][kt * 32 + acol];
        acc[0][0] = __builtin_amdgcn_mfma_f32_16x16x32_bf16(ah0, cb0h, acc[0][0], 0, 0, 0);
        acc[0][1] = __builtin_amdgcn_mfma_f32_16x16x32_bf16(ah0, cb1h, acc[0][1], 0, 0, 0);
        acc[1][0] = __builtin_amdgcn_mfma_f32_16x16x32_bf16(ah1, cb0h, acc[1][0], 0, 0, 0);
        acc[1][1] = __builtin_amdgcn_mfma_f32_16x16x32_bf16(ah1, cb1h, acc[1][1], 0, 0, 0);
        acc[0][0] = __builtin_amdgcn_mfma_f32_16x16x32_bf16(al0, cb0h, acc[0][0], 0, 0, 0);
        acc[0][1] = __builtin_amdgcn_mfma_f32_16x16x32_bf16(al0, cb1h, acc[0][1], 0, 0, 0);
        acc[1][0] = __builtin_amdgcn_mfma_f32_16x16x32_bf16(al1, cb0h, acc[1][0], 0, 0, 0);
        acc[1][1] = __builtin_amdgcn_mfma_f32_16x16x32_bf16(al1, cb1h, acc[1][1], 0, 0, 0);
        acc[0][0] = __builtin_amdgcn_mfma_f32_16x16x32_bf16(ah0, cb0l, acc[0][0], 0, 0, 0);
        acc[0][1] = __builtin_amdgcn_mfma_f32_16x16x32_bf16(ah0, cb1l, acc[0][1], 0, 0, 0);
        acc[1][0] = __builtin_amdgcn_mfma_f32_16x16x32_bf16(ah1, cb0l, acc[1][0], 0, 0, 0);
        acc[1][1] = __builtin_amdgcn_mfma_f32_16x16x32_bf16(ah1, cb1l, acc[1][1], 0, 0, 0);
        cb0h = nb0h; cb1h = nb1h; cb0l = nb0l; cb1l = nb1l;
      }
#pragma unroll
      for (int m = 0; m < 2; ++m)
#pragma unroll
        for (int t = 0; t < 2; ++t) {
          int brow = bg * 32 + m * 16 + (lane >> 4) * 4;
          int col = nc * 128 + (w * 2 + t) * 16 + (lane & 15);
          float* zb = P.zX + ((size_t)c * NB + brow) * 2048 + col;
#pragma unroll
          for (int rr = 0; rr < 4; ++rr) stF(zb + (size_t)rr * 2048, acc[m][t][rr]);
        }
    }
    __syncthreads();  // drains vmcnt across all waves -> zX visible at L3
    if (tid == 0) stU(&P.flags[bid], (unsigned)(i + 1));
    return;
  }
  // ================= B part =================
  int wb = bid - 384;
  unsigned target = (unsigned)(i + 1);
  if (wb < 64) {  // gate1, s = i-1, consumes c 0..3
    int s = i - 1;
    if (s < 0 || s >= NT) return;
    wait_flags(P.flags, 0, target);
    bool z = (s == 0);
    do_gateM(P.zX, 0, 3, P.b_rnn1,
             z ? P.zerob : P.c1 + (size_t)((s - 1) & 1) * NB * 512,
             z ? P.zerob : P.h1 + (size_t)((s - 1) & 1) * NB * 512, z,
             P.mel_mask + (size_t)s * NB,
             P.h1 + (size_t)(s & 1) * NB * 512,
             P.c1 + (size_t)(s & 1) * NB * 512, wb, 2 * tid);
    return;
  }
  if (wb < 128) {  // gate2, s = i-2, consumes c 8..11
    int s = i - 2;
    if (s < 0 || s >= NT) return;
    wait_flags(P.flags, 128, target);
    bool z = (s == 0);
    do_gateM(P.zX, 8, 11, P.b_rnn2,
             z ? P.zerob : P.c2 + (size_t)((s - 1) & 1) * NB * 512,
             z ? P.zerob : P.outs + (size_t)(s - 1) * NB * 512, z,
             P.mel_mask + (size_t)s * NB,
             P.outs + (size_t)s * NB * 512,
             P.c2 + (size_t)(s & 1) * NB * 512, wb - 64, 2 * tid);
    return;
  }
  // attention, s = i, consumes c 4..7
  int s = i;
  if (s >= NT) return;
  wait_flags(P.flags, 64, target);
  int b = wb - 128;
  float* sh = (float*)&xsh[0][0];
  float* ah_s = sh;
  float* red_s = sh + 512;
  float* pr_s = sh + 768;
  float* abk = sh + 800;
  float* phi_s = sh + 896;
  float m = P.mel_mask[(size_t)s * NB + b];
  bool z = (s == 0);
  int pp = (s - 1) & 1;
  {
    int j = 2 * tid;
    float2 zi = *(const float2*)(P.b_att + j);
    float2 zf = *(const float2*)(P.b_att + 512 + j);
    float2 zg = *(const float2*)(P.b_att + 1024 + j);
    float2 zo = *(const float2*)(P.b_att + 1536 + j);
    for (int cc = 4; cc <= 7; ++cc) {
      const float* q = P.zX + ((size_t)cc * NB + b) * 2048 + j;
      float2 a = ldF2(q), f2 = ldF2(q + 512), g2 = ldF2(q + 1024), o2 = ldF2(q + 1536);
      zi.x += a.x; zi.y += a.y;
      zf.x += f2.x; zf.y += f2.y;
      zg.x += g2.x; zg.y += g2.y;
      zo.x += o2.x; zo.y += o2.y;
    }
    float2 cp = z ? make_float2(0.f, 0.f)
                  : *(const float2*)(P.ac + (size_t)pp * NB * 512 + (size_t)b * 512 + j);
    float2 hp = z ? make_float2(0.f, 0.f)
                  : *(const float2*)(P.ah + (size_t)pp * NB * 512 + (size_t)b * 512 + j);
    float cnx = sigm(zf.x) * cp.x + sigm(zi.x) * tanhf(zg.x);
    float cny = sigm(zf.y) * cp.y + sigm(zi.y) * tanhf(zg.y);
    float hrx = sigm(zo.x) * tanhf(cnx);
    float hry = sigm(zo.y) * tanhf(cny);
    ah_s[j] = hrx;
    ah_s[j + 1] = hry;
    *(float2*)(P.ah + (size_t)(s & 1) * NB * 512 + (size_t)b * 512 + j) =
        make_float2(m * hrx + (1.f - m) * hp.x, m * hry + (1.f - m) * hp.y);
    *(float2*)(P.ac + (size_t)(s & 1) * NB * 512 + (size_t)b * 512 + j) =
        make_float2(m * cnx + (1.f - m) * cp.x, m * cny + (1.f - m) * cp.y);
  }
  __syncthreads();
  {
    int cc2 = tid & 31, ch = tid >> 5;
    float ssum = 0.f;
    if (cc2 < 30)
      for (int k = ch * 64; k < ch * 64 + 64; ++k) ssum += ah_s[k] * P.w_proj[k * 30 + cc2];
    red_s[ch * 32 + cc2] = ssum;
  }
  __syncthreads();
  if (tid < 30) {
    float ssum = P.b_proj[tid];
    for (int ch = 0; ch < 8; ++ch) ssum += red_s[ch * 32 + tid];
    pr_s[tid] = ssum;
  }
  __syncthreads();
  if (tid < WMc) {
    float kp = z ? 0.f : P.ak[(size_t)pp * NB * AKS + (size_t)b * AKS + tid];
    float a_t = softplusf(pr_s[tid]);
    float b_t = softplusf(pr_s[WMc + tid]);
    float k_t = kp + softplusf(pr_s[2 * WMc + tid]);
    abk[tid] = a_t;
    abk[32 + tid] = b_t;
    abk[64 + tid] = k_t;
    P.ak[(size_t)(s & 1) * NB * AKS + (size_t)b * AKS + tid] = m * k_t + (1.f - m) * kp;
  }
  __syncthreads();
  {
    int u = tid;
    float ssum = 0.f;
#pragma unroll
    for (int gg = 0; gg < WMc; ++gg) {
      float dd = abk[64 + gg] - (float)u;
      ssum += abk[gg] * expf(-abk[32 + gg] * dd * dd);
    }
    phi_s[u] = ssum * P.text_mask[u * NB + b];
  }
  __syncthreads();
  {
    int dcol = tid;
    float ssum = 0.f;
#pragma unroll 8
    for (int u = 0; u < NU; ++u)
      ssum += phi_s[u] * __builtin_nontemporal_load(P.ctx + ((size_t)u * NB + b) * 256 + dcol);
    float wprev = z ? 0.f : P.aw[(size_t)pp * NB * 256 + (size_t)b * 256 + dcol];
    P.aw[(size_t)(s & 1) * NB * 256 + (size_t)b * 256 + dcol] = m * ssum + (1.f - m) * wprev;
  }
}

// =====================================================================================
extern "C" void kernel_launch(void* const* d_in, const int* in_sizes, int n_in,
                              void* d_out, int out_size, void* d_ws, size_t ws_size,
                              hipStream_t stream) {
  const float* in_mels = (const float*)d_in[0];
  const float* mel_mask = (const float*)d_in[1];
  const int* text = (const int*)d_in[2];
  const float* text_mask = (const float*)d_in[3];
  const float* w_pre1 = (const float*)d_in[4];
  const float* b_pre1 = (const float*)d_in[5];
  const float* w_pre2 = (const float*)d_in[6];
  const float* b_pre2 = (const float*)d_in[7];
  const float* emb = (const float*)d_in[8];
  const float* conv_w0 = (const float*)d_in[9];
  const float* conv_b0 = (const float*)d_in[10];
  const float* conv_w1 = (const float*)d_in[11];
  const float* conv_b1 = (const float*)d_in[12];
  const float* conv_w2 = (const float*)d_in[13];
  const float* conv_b2 = (const float*)d_in[14];
  const float* w_bif = (const float*)d_in[15];
  const float* b_bif = (const float*)d_in[16];
  const float* w_bib = (const float*)d_in[17];
  const float* b_bib = (const float*)d_in[18];
  const float* w_att = (const float*)d_in[19];
  const float* b_att = (const float*)d_in[20];
  const float* w_proj = (const float*)d_in[21];
  const float* b_proj = (const float*)d_in[22];
  const float* w_rnn1 = (const float*)d_in[23];
  const float* b_rnn1 = (const float*)d_in[24];
  const float* w_rnn2 = (const float*)d_in[25];
  const float* b_rnn2 = (const float*)d_in[26];
  const float* w_outp = (const float*)d_in[27];
  const float* b_outp = (const float*)d_in[28];

  float* ws = (float*)d_ws;
  size_t off = 0;
  auto alloc = [&](size_t n) {
    float* p = ws + off;
    off += (n + 63) & ~(size_t)63;
    return p;
  };
  float* corr = alloc((size_t)NT * NB * PREc);
  float* embx = alloc((size_t)NB * NU * EMBc);
  float* wpkR = alloc(WSZ);  // hi+lo planes (30.4MB); also prenet tmp / conv ping
  float* zX = alloc((size_t)12 * NB * 2048);
  float* ctx = alloc((size_t)NU * NB * 2 * ENCc);  // also conv pong
  float* convbuf = alloc((size_t)NB * NU * NFc);   // final conv output (encoder input)
  float* aw = alloc((size_t)2 * NB * 2 * ENCc);
  float* ak = alloc((size_t)2 * NB * AKS);
  float* ah = alloc((size_t)2 * NB * DECc);
  float* ac = alloc((size_t)2 * NB * DECc);
  float* h1 = alloc((size_t)2 * NB * DECc);
  float* c1 = alloc((size_t)2 * NB * DECc);
  float* c2 = alloc((size_t)2 * NB * DECc);
  float* outs = alloc((size_t)NT * NB * DECc);  // h2 rows; encoder zx (fp16) overlays
  float* weff0 = alloc((size_t)5 * EMBc * NFc);
  float* beff0 = alloc(NFc);
  float* weff1 = alloc((size_t)5 * NFc * NFc);
  float* beff1 = alloc(NFc);
  float* weff2 = alloc((size_t)5 * NFc * NFc);
  float* beff2 = alloc(NFc);
  float* zerob = alloc(1024);
  float* flagsf = alloc(512);
  unsigned* flags = (unsigned*)flagsf;

  unsigned short* Wpk = (unsigned short*)wpkR;
  _Float16* zx = (_Float16*)outs;  // dead before decoder writes outs
  float* tmp = wpkR;
  float* convA = wpkR;
  float* convB = ctx;

  hipMemsetAsync(zerob, 0, 1024 * sizeof(float), stream);
  hipMemsetAsync(flags, 0, 512 * sizeof(unsigned), stream);

  // ---- prenet ----
  k_dense<NMELc, PREc, 8><<<NT * NB / 8, 128, 0, stream>>>(in_mels, w_pre1, b_pre1, tmp, NT * NB);
  k_dense<PREc, PREc, 8><<<NT * NB / 8, 128, 0, stream>>>(tmp, w_pre2, b_pre2, corr, NT * NB);

  // ---- text conv stacks: embx -> convB -> convA -> convbuf ----
  k_embed<<<(NB * NU * EMBc + 255) / 256, 256, 0, stream>>>(text, emb, embx);
  k_weff<EMBc><<<(5 * EMBc * NFc + 255) / 256, 256, 0, stream>>>(conv_w0, conv_b0, weff0, beff0);
  k_weff<NFc><<<(5 * NFc * NFc + 255) / 256, 256, 0, stream>>>(conv_w1, conv_b1, weff1, beff1);
  k_weff<NFc><<<(5 * NFc * NFc + 255) / 256, 256, 0, stream>>>(conv_w2, conv_b2, weff2, beff2);
  k_conv<EMBc, false><<<dim3(NU / 8, NB), 128, 0, stream>>>(embx, weff0, beff0, convB);
  k_conv<NFc, true><<<dim3(NU / 8, NB), 128, 0, stream>>>(convB, weff1, beff1, convA);
  k_conv<NFc, true><<<dim3(NU / 8, NB), 128, 0, stream>>>(convA, weff2, beff2, convbuf);

  // ---- prepack decoder weights (frees wpkR conv use) ----
  k_wcvt<<<dim3(116, 4), 256, 0, stream>>>(w_rnn1, w_att, w_rnn2, Wpk);

  // ---- encoder: x-part precompute + persistent block-local BiLSTM ----
  k_zx<<<dim3(512, 8), 512, 0, stream>>>(w_bif, b_bif, w_bib, b_bib, convbuf, zx);
  k_encP2<<<32, 256, 0, stream>>>(w_bif, w_bib, zx, text_mask, ctx);

  // ---- decoder: ONE merged launch per pipeline slot ----
  DecMp M;
  M.corr = corr; M.Wpk = Wpk;
  M.mel_mask = mel_mask; M.text_mask = text_mask; M.ctx = ctx;
  M.b_att = b_att; M.b_rnn1 = b_rnn1; M.b_rnn2 = b_rnn2;
  M.w_proj = w_proj; M.b_proj = b_proj;
  M.aw = aw; M.ak = ak; M.ah = ah; M.ac = ac;
  M.h1 = h1; M.c1 = c1; M.c2 = c2; M.outs = outs; M.zerob = zerob;
  M.zX = zX; M.flags = flags;
  for (int i = 0; i <= NT + 1; ++i) {
    k_decM<<<576, 256, 0, stream>>>(M, i);
  }

  // ---- output projection ----
  k_dense<DECc, NMELc, 8><<<NT * NB / 8, 128, 0, stream>>>(outs, w_outp, b_outp, (float*)d_out,
                                                           NT * NB);
}